// Round 1
// baseline (3379.565 us; speedup 1.0000x reference)
//
#include <hip/hip_runtime.h>
#include <math.h>

// GNN message-passing layer, fp32 baseline.
// Pipeline:
//   agg = 0
//   msg_kernel:   messages = [nodes[snd] | edge_attr] @ Wm^T ; atomic-scatter into agg[rcv]
//   node_kernel<256,0>: h        = LN(relu([nodes|agg] @ W1^T + b1))
//   node_kernel<128,1>: node_out = LN(relu(h @ W2^T + b2))        (overwrites agg buf)
//   node_kernel<128,2>: out      = LN(nodes @ Wn^T + node_out)

#define THREADS 256
#define BM 64
#define BN 128
#define BK 32
#define AP 36    // As row pitch (floats), multiple of 4, odd/32 bank spread
#define BP 132   // Bs/Cs row pitch (floats)

struct GemmSmem {
  float As[BM][AP];
  float Bs[BK][BP];
};
struct EpiSmem {
  float Cs[BM][BP];
  float psum[BM][4];
  float psq[BM][4];
  float mu[BM];
  float rs[BM];
};
union NodeSmem {
  GemmSmem g;
  EpiSmem e;
};

__device__ __forceinline__ void gemm_compute(const GemmSmem& sm, int tx, int r0,
                                             float acc[8][4]) {
#pragma unroll
  for (int kk = 0; kk < BK; kk += 4) {
    float4 b0 = *(const float4*)&sm.Bs[kk + 0][4 * tx];
    float4 b1 = *(const float4*)&sm.Bs[kk + 1][4 * tx];
    float4 b2 = *(const float4*)&sm.Bs[kk + 2][4 * tx];
    float4 b3 = *(const float4*)&sm.Bs[kk + 3][4 * tx];
#pragma unroll
    for (int i = 0; i < 8; ++i) {
      float4 a = *(const float4*)&sm.As[r0 + i][kk];
      acc[i][0] += a.x * b0.x + a.y * b1.x + a.z * b2.x + a.w * b3.x;
      acc[i][1] += a.x * b0.y + a.y * b1.y + a.z * b2.y + a.w * b3.y;
      acc[i][2] += a.x * b0.z + a.y * b1.z + a.z * b2.z + a.w * b3.z;
      acc[i][3] += a.x * b0.w + a.y * b1.w + a.z * b2.w + a.w * b3.w;
    }
  }
}

template <int KT>
__device__ __forceinline__ void load_B(GemmSmem& sm, const float* __restrict__ W,
                                       int kc, int tid) {
  // Bs[kk][j] = W[j][kc+kk]; W is [128][KT] row-major
#pragma unroll
  for (int c = 0; c < 4; ++c) {
    int f = tid + THREADS * c;   // float4 index in [128 rows][8 f4/row]
    int j = f >> 3, u = f & 7;
    float4 v = *(const float4*)&W[(size_t)j * KT + kc + 4 * u];
    sm.Bs[4 * u + 0][j] = v.x;
    sm.Bs[4 * u + 1][j] = v.y;
    sm.Bs[4 * u + 2][j] = v.z;
    sm.Bs[4 * u + 3][j] = v.w;
  }
}

// ---------------- edge message GEMM + scatter ----------------
__global__ __launch_bounds__(THREADS, 2) void msg_kernel(
    const float* __restrict__ nodes, const int* __restrict__ eidx,
    const float* __restrict__ eattr, const float* __restrict__ Wm,
    float* __restrict__ agg, int E, int Nn) {
  __shared__ GemmSmem sm;
  __shared__ int sdr[BM];
  __shared__ int rcv[BM];
  const int tid = threadIdx.x;
  const int e0 = blockIdx.x * BM;
  if (tid < BM) {
    int e = e0 + tid;
    if (e >= E) e = E - 1;
    sdr[tid] = eidx[e];
    rcv[tid] = eidx[E + e];
  }
  __syncthreads();

  const int tx = tid & 31;
  const int r0 = (tid >> 5) * 8;
  float acc[8][4];
#pragma unroll
  for (int i = 0; i < 8; ++i)
#pragma unroll
    for (int u = 0; u < 4; ++u) acc[i][u] = 0.f;

  const int KT = 160;
  for (int kc = 0; kc < KT; kc += BK) {
    // A chunk: 64 edges x 32 k, gathered
#pragma unroll
    for (int c = 0; c < 2; ++c) {
      int f = tid + THREADS * c;   // float4 index in [64][8]
      int e = f >> 3, u = f & 7;
      int k = kc + 4 * u;
      int eg = e0 + e;
      if (eg >= E) eg = E - 1;
      float4 v;
      if (k < 128) {
        v = *(const float4*)&nodes[(size_t)sdr[e] * 128 + k];
      } else {
        v = *(const float4*)&eattr[(size_t)eg * 32 + (k - 128)];
      }
      *(float4*)&sm.As[e][4 * u] = v;
    }
    load_B<160>(sm, Wm, kc, tid);
    __syncthreads();
    gemm_compute(sm, tx, r0, acc);
    __syncthreads();
  }

  // scatter-add epilogue
#pragma unroll
  for (int i = 0; i < 8; ++i) {
    int e = e0 + r0 + i;
    if (e < E) {
      float* dst = &agg[(size_t)rcv[r0 + i] * 128 + 4 * tx];
      atomicAdd(dst + 0, acc[i][0]);
      atomicAdd(dst + 1, acc[i][1]);
      atomicAdd(dst + 2, acc[i][2]);
      atomicAdd(dst + 3, acc[i][3]);
    }
  }
}

// ---------------- node GEMM + bias/relu/residual + LayerNorm ----------------
// MODE 0: A = [A0 | A1] (K=256), +bias, relu, LN
// MODE 1: A = A0 (K=128), +bias, relu, LN
// MODE 2: A = A0 (K=128), no bias, + residual A1[row], LN
template <int KT, int MODE>
__global__ __launch_bounds__(THREADS, 2) void node_kernel(
    const float* __restrict__ A0, const float* __restrict__ A1,
    const float* __restrict__ W, const float* __restrict__ bias,
    const float* __restrict__ g, const float* __restrict__ bln,
    float* __restrict__ out, int Nn) {
  __shared__ NodeSmem sm;
  const int tid = threadIdx.x;
  const int row0 = blockIdx.x * BM;
  const int tx = tid & 31;
  const int r0 = (tid >> 5) * 8;

  float acc[8][4];
#pragma unroll
  for (int i = 0; i < 8; ++i)
#pragma unroll
    for (int u = 0; u < 4; ++u) acc[i][u] = 0.f;

  for (int kc = 0; kc < KT; kc += BK) {
#pragma unroll
    for (int c = 0; c < 2; ++c) {
      int f = tid + THREADS * c;
      int r = f >> 3, u = f & 7;
      int k = kc + 4 * u;
      int row = row0 + r;
      if (row >= Nn) row = Nn - 1;
      float4 v;
      if (MODE == 0) {
        if (k < 128)
          v = *(const float4*)&A0[(size_t)row * 128 + k];
        else
          v = *(const float4*)&A1[(size_t)row * 128 + (k - 128)];
      } else {
        v = *(const float4*)&A0[(size_t)row * 128 + k];
      }
      *(float4*)&sm.g.As[r][4 * u] = v;
    }
    load_B<KT>(sm.g, W, kc, tid);
    __syncthreads();
    gemm_compute(sm.g, tx, r0, acc);
    __syncthreads();
  }

  // epilogue: stage C in LDS with bias/relu/residual applied
  float4 bv = make_float4(0.f, 0.f, 0.f, 0.f);
  if (MODE < 2) bv = *(const float4*)&bias[4 * tx];
#pragma unroll
  for (int i = 0; i < 8; ++i) {
    int r = r0 + i;
    float v0 = acc[i][0] + bv.x;
    float v1 = acc[i][1] + bv.y;
    float v2 = acc[i][2] + bv.z;
    float v3 = acc[i][3] + bv.w;
    if (MODE == 2) {
      int row = row0 + r;
      if (row >= Nn) row = Nn - 1;
      float4 rsd = *(const float4*)&A1[(size_t)row * 128 + 4 * tx];
      v0 += rsd.x; v1 += rsd.y; v2 += rsd.z; v3 += rsd.w;
    }
    if (MODE < 2) {
      v0 = fmaxf(v0, 0.f); v1 = fmaxf(v1, 0.f);
      v2 = fmaxf(v2, 0.f); v3 = fmaxf(v3, 0.f);
    }
    float4 vv = make_float4(v0, v1, v2, v3);
    *(float4*)&sm.e.Cs[r][4 * tx] = vv;
  }
  __syncthreads();

  // row stats: 4 threads per row
  {
    int q = tid & 3, r = tid >> 2;
    float s = 0.f, s2 = 0.f;
#pragma unroll 8
    for (int j = q * 32; j < q * 32 + 32; ++j) {
      float x = sm.e.Cs[r][j];
      s += x;
      s2 += x * x;
    }
    sm.e.psum[r][q] = s;
    sm.e.psq[r][q] = s2;
  }
  __syncthreads();
  if (tid < BM) {
    float S = 0.f, S2 = 0.f;
#pragma unroll
    for (int q = 0; q < 4; ++q) {
      S += sm.e.psum[tid][q];
      S2 += sm.e.psq[tid][q];
    }
    float m = S * (1.f / 128.f);
    float var = S2 * (1.f / 128.f) - m * m;
    sm.e.mu[tid] = m;
    sm.e.rs[tid] = rsqrtf(var + 1e-5f);
  }
  __syncthreads();

  // normalized coalesced store
#pragma unroll 4
  for (int s = 0; s < 32; ++s) {
    int flat = tid + THREADS * s;   // 64*128 elements
    int r = flat >> 7, j = flat & 127;
    int row = row0 + r;
    if (row < Nn) {
      float x = sm.e.Cs[r][j];
      out[(size_t)row * 128 + j] =
          (x - sm.e.mu[r]) * sm.e.rs[r] * g[j] + bln[j];
    }
  }
}

extern "C" void kernel_launch(void* const* d_in, const int* in_sizes, int n_in,
                              void* d_out, int out_size, void* d_ws, size_t ws_size,
                              hipStream_t stream) {
  const float* nodes = (const float*)d_in[0];
  const int* eidx    = (const int*)d_in[1];
  const float* eattr = (const float*)d_in[2];
  const float* Wm    = (const float*)d_in[3];
  const float* Wn    = (const float*)d_in[4];
  const float* W1    = (const float*)d_in[5];
  const float* b1    = (const float*)d_in[6];
  const float* g1    = (const float*)d_in[7];
  const float* bl1   = (const float*)d_in[8];
  const float* W2    = (const float*)d_in[9];
  const float* b2    = (const float*)d_in[10];
  const float* g2    = (const float*)d_in[11];
  const float* bl2   = (const float*)d_in[12];
  const float* gf    = (const float*)d_in[13];
  const float* blf   = (const float*)d_in[14];
  float* out = (float*)d_out;

  const int Nn = in_sizes[0] / 128;   // 100000
  const int E  = in_sizes[2] / 32;    // 800000

  float* agg = (float*)d_ws;                  // [Nn,128]; reused as node_out
  float* h   = agg + (size_t)Nn * 128;        // [Nn,128]

  hipMemsetAsync(agg, 0, (size_t)Nn * 128 * sizeof(float), stream);

  const int egrid = (E + BM - 1) / BM;
  const int ngrid = (Nn + BM - 1) / BM;

  msg_kernel<<<egrid, THREADS, 0, stream>>>(nodes, eidx, eattr, Wm, agg, E, Nn);
  node_kernel<256, 0><<<ngrid, THREADS, 0, stream>>>(nodes, agg, W1, b1, g1, bl1, h, Nn);
  node_kernel<128, 1><<<ngrid, THREADS, 0, stream>>>(h, nullptr, W2, b2, g2, bl2, agg, Nn);
  node_kernel<128, 2><<<ngrid, THREADS, 0, stream>>>(nodes, agg, Wn, nullptr, gf, blf, out, Nn);
}

// Round 2
// 621.418 us; speedup vs baseline: 5.4385x; 5.4385x over previous
//
#include <hip/hip_runtime.h>
#include <math.h>

// GNN message-passing layer, bf16-MFMA version.
//   agg = 0
//   msg_kernel:   messages = [nodes[snd] | edge_attr] @ Wm^T ; atomic-scatter into agg[rcv]
//   node_kernel<256,0>: h        = LN(relu([nodes|agg] @ W1^T + b1))
//   node_kernel<128,1>: node_out = LN(relu(h @ W2^T + b2))
//   node_kernel<128,2>: out      = LN(nodes @ Wn^T + node_out)
// All GEMMs: fp32 global -> bf16 LDS tiles -> v_mfma_f32_16x16x32_bf16, fp32 acc.
// Block tile M=64 x N=128, BK=32. 4 waves in 2x2: each wave 32 rows x 64 cols
// (2x4 tiles of 16x16). A/B LDS pitch 40 bf16 (80 B) -> 2-way-max bank aliasing (free).

#define THREADS 256
#define BM 64
#define BK 32
#define APB 40   // LDS row pitch in bf16 for A and B tiles
#define BP 132   // Cs row pitch (floats)

typedef __attribute__((ext_vector_type(8))) short bf16x8;
typedef __attribute__((ext_vector_type(4))) float f32x4;

struct GemmSmem {
  unsigned short As[BM][APB];    // [row][k] bf16
  unsigned short Bs[128][APB];   // [n][k]   bf16  (W is [n][K] row-major)
};
struct EpiSmem {
  float Cs[BM][BP];
  float psum[BM][4];
  float psq[BM][4];
  float mu[BM];
  float rs[BM];
};
union NodeSmem {
  GemmSmem g;
  EpiSmem e;
};

__device__ __forceinline__ unsigned short f2bf(float x) {
  union { float f; unsigned u; } c;
  c.f = x;
  unsigned u = c.u;
  u += 0x7fffu + ((u >> 16) & 1u);   // round-to-nearest-even
  return (unsigned short)(u >> 16);
}

__device__ __forceinline__ void store_bf4(unsigned short* dst, float4 v) {
  ushort4 p;
  p.x = f2bf(v.x); p.y = f2bf(v.y); p.z = f2bf(v.z); p.w = f2bf(v.w);
  *(ushort4*)dst = p;
}

// Stage B chunk: Bs[n][kk] = W[n][kc+kk], n=0..127, kk=0..31
template <int KT>
__device__ __forceinline__ void load_B(GemmSmem& sm, const float* __restrict__ W,
                                       int kc, int tid) {
#pragma unroll
  for (int c = 0; c < 4; ++c) {
    int f = tid + THREADS * c;   // float4 index in [128][8]
    int n = f >> 3, u = f & 7;
    float4 v = *(const float4*)&W[(size_t)n * KT + kc + 4 * u];
    store_bf4(&sm.Bs[n][4 * u], v);
  }
}

// One K-chunk of MFMA work. Wave layout: wid = tid>>6, wy=wid>>1, wx=wid&1.
__device__ __forceinline__ void gemm_chunk(const GemmSmem& sm, int tid,
                                           f32x4 acc[2][4]) {
  const int lane = tid & 63;
  const int quad = lane >> 4;
  const int lm = lane & 15;
  const int wid = tid >> 6;
  const int wy = wid >> 1, wx = wid & 1;

  bf16x8 af[2], bf[4];
#pragma unroll
  for (int mt = 0; mt < 2; ++mt)
    af[mt] = *(const bf16x8*)&sm.As[32 * wy + 16 * mt + lm][quad * 8];
#pragma unroll
  for (int nt = 0; nt < 4; ++nt)
    bf[nt] = *(const bf16x8*)&sm.Bs[64 * wx + 16 * nt + lm][quad * 8];
#pragma unroll
  for (int mt = 0; mt < 2; ++mt)
#pragma unroll
    for (int nt = 0; nt < 4; ++nt)
      acc[mt][nt] = __builtin_amdgcn_mfma_f32_16x16x32_bf16(
          af[mt], bf[nt], acc[mt][nt], 0, 0, 0);
}

// ---------------- edge message GEMM + atomic scatter ----------------
__global__ __launch_bounds__(THREADS, 4) void msg_kernel(
    const float* __restrict__ nodes, const int* __restrict__ eidx,
    const float* __restrict__ eattr, const float* __restrict__ Wm,
    float* __restrict__ agg, int E) {
  __shared__ GemmSmem sm;
  __shared__ int sdr[BM];
  __shared__ int rcv[BM];
  const int tid = threadIdx.x;
  const int e0 = blockIdx.x * BM;
  if (tid < BM) {
    int e = e0 + tid;
    if (e >= E) e = E - 1;
    sdr[tid] = eidx[e];
    rcv[tid] = eidx[E + e];
  }
  __syncthreads();

  f32x4 acc[2][4];
#pragma unroll
  for (int mt = 0; mt < 2; ++mt)
#pragma unroll
    for (int nt = 0; nt < 4; ++nt) acc[mt][nt] = (f32x4)0.f;

  for (int kc = 0; kc < 160; kc += BK) {
#pragma unroll
    for (int c = 0; c < 2; ++c) {
      int f = tid + THREADS * c;   // float4 index in [64][8]
      int e = f >> 3, u = f & 7;
      int k = kc + 4 * u;
      float4 v;
      if (k < 128) {
        v = *(const float4*)&nodes[(size_t)sdr[e] * 128 + k];
      } else {
        int eg = e0 + e;
        if (eg >= E) eg = E - 1;
        v = *(const float4*)&eattr[(size_t)eg * 32 + (k - 128)];
      }
      store_bf4(&sm.As[e][4 * u], v);
    }
    load_B<160>(sm, Wm, kc, tid);
    __syncthreads();
    gemm_chunk(sm, tid, acc);
    __syncthreads();
  }

  // scatter-add epilogue
  const int lane = tid & 63;
  const int quad = lane >> 4;
  const int lm = lane & 15;
  const int wid = tid >> 6;
  const int wy = wid >> 1, wx = wid & 1;
#pragma unroll
  for (int mt = 0; mt < 2; ++mt) {
#pragma unroll
    for (int i = 0; i < 4; ++i) {
      int r = 32 * wy + 16 * mt + quad * 4 + i;
      int e = e0 + r;
      if (e < E) {
        float* dst = &agg[(size_t)rcv[r] * 128 + lm];
#pragma unroll
        for (int nt = 0; nt < 4; ++nt)
          atomicAdd(dst + 64 * wx + 16 * nt, acc[mt][nt][i]);
      }
    }
  }
}

// ---------------- node GEMM + bias/relu/residual + LayerNorm ----------------
// MODE 0: A = [A0 | A1] (K=256), +bias, relu, LN
// MODE 1: A = A0 (K=128), +bias, relu, LN
// MODE 2: A = A0 (K=128), no bias, + residual A1[row], LN
template <int KT, int MODE>
__global__ __launch_bounds__(THREADS, 4) void node_kernel(
    const float* __restrict__ A0, const float* __restrict__ A1,
    const float* __restrict__ W, const float* __restrict__ bias,
    const float* __restrict__ g, const float* __restrict__ bln,
    float* __restrict__ out, int Nn) {
  __shared__ NodeSmem sm;
  const int tid = threadIdx.x;
  const int row0 = blockIdx.x * BM;

  f32x4 acc[2][4];
#pragma unroll
  for (int mt = 0; mt < 2; ++mt)
#pragma unroll
    for (int nt = 0; nt < 4; ++nt) acc[mt][nt] = (f32x4)0.f;

  for (int kc = 0; kc < KT; kc += BK) {
#pragma unroll
    for (int c = 0; c < 2; ++c) {
      int f = tid + THREADS * c;
      int r = f >> 3, u = f & 7;
      int k = kc + 4 * u;
      int row = row0 + r;
      if (row >= Nn) row = Nn - 1;
      float4 v;
      if (MODE == 0) {
        if (k < 128)
          v = *(const float4*)&A0[(size_t)row * 128 + k];
        else
          v = *(const float4*)&A1[(size_t)row * 128 + (k - 128)];
      } else {
        v = *(const float4*)&A0[(size_t)row * 128 + k];
      }
      store_bf4(&sm.g.As[r][4 * u], v);
    }
    load_B<KT>(sm.g, W, kc, tid);
    __syncthreads();
    gemm_chunk(sm.g, tid, acc);
    __syncthreads();
  }

  // epilogue: acc -> Cs with bias/relu/residual applied
  const int lane = tid & 63;
  const int quad = lane >> 4;
  const int lm = lane & 15;
  const int wid = tid >> 6;
  const int wy = wid >> 1, wx = wid & 1;

  float bval[4] = {0.f, 0.f, 0.f, 0.f};
  if (MODE < 2) {
#pragma unroll
    for (int nt = 0; nt < 4; ++nt) bval[nt] = bias[64 * wx + 16 * nt + lm];
  }
#pragma unroll
  for (int mt = 0; mt < 2; ++mt) {
#pragma unroll
    for (int i = 0; i < 4; ++i) {
      int r = 32 * wy + 16 * mt + quad * 4 + i;
      int row = row0 + r;
      if (row >= Nn) row = Nn - 1;
#pragma unroll
      for (int nt = 0; nt < 4; ++nt) {
        int col = 64 * wx + 16 * nt + lm;
        float v = acc[mt][nt][i];
        if (MODE < 2) v = fmaxf(v + bval[nt], 0.f);
        if (MODE == 2) v += A1[(size_t)row * 128 + col];
        sm.e.Cs[r][col] = v;
      }
    }
  }
  __syncthreads();

  // row stats: 4 threads per row
  {
    int q = tid & 3, r = tid >> 2;
    float s = 0.f, s2 = 0.f;
#pragma unroll 8
    for (int j = q * 32; j < q * 32 + 32; ++j) {
      float x = sm.e.Cs[r][j];
      s += x;
      s2 += x * x;
    }
    sm.e.psum[r][q] = s;
    sm.e.psq[r][q] = s2;
  }
  __syncthreads();
  if (tid < BM) {
    float S = 0.f, S2 = 0.f;
#pragma unroll
    for (int q = 0; q < 4; ++q) {
      S += sm.e.psum[tid][q];
      S2 += sm.e.psq[tid][q];
    }
    float m = S * (1.f / 128.f);
    float var = S2 * (1.f / 128.f) - m * m;
    sm.e.mu[tid] = m;
    sm.e.rs[tid] = rsqrtf(var + 1e-5f);
  }
  __syncthreads();

  // normalized coalesced store
#pragma unroll 4
  for (int s = 0; s < 32; ++s) {
    int flat = tid + THREADS * s;   // 64*128 elements
    int r = flat >> 7, j = flat & 127;
    int row = row0 + r;
    if (row < Nn) {
      float x = sm.e.Cs[r][j];
      out[(size_t)row * 128 + j] =
          (x - sm.e.mu[r]) * sm.e.rs[r] * g[j] + bln[j];
    }
  }
}

extern "C" void kernel_launch(void* const* d_in, const int* in_sizes, int n_in,
                              void* d_out, int out_size, void* d_ws, size_t ws_size,
                              hipStream_t stream) {
  const float* nodes = (const float*)d_in[0];
  const int* eidx    = (const int*)d_in[1];
  const float* eattr = (const float*)d_in[2];
  const float* Wm    = (const float*)d_in[3];
  const float* Wn    = (const float*)d_in[4];
  const float* W1    = (const float*)d_in[5];
  const float* b1    = (const float*)d_in[6];
  const float* g1    = (const float*)d_in[7];
  const float* bl1   = (const float*)d_in[8];
  const float* W2    = (const float*)d_in[9];
  const float* b2    = (const float*)d_in[10];
  const float* g2    = (const float*)d_in[11];
  const float* bl2   = (const float*)d_in[12];
  const float* gf    = (const float*)d_in[13];
  const float* blf   = (const float*)d_in[14];
  float* out = (float*)d_out;

  const int Nn = in_sizes[0] / 128;   // 100000
  const int E  = in_sizes[2] / 32;    // 800000

  float* agg = (float*)d_ws;                  // [Nn,128]; reused as node_out
  float* h   = agg + (size_t)Nn * 128;        // [Nn,128]

  hipMemsetAsync(agg, 0, (size_t)Nn * 128 * sizeof(float), stream);

  const int egrid = (E + BM - 1) / BM;
  const int ngrid = (Nn + BM - 1) / BM;

  msg_kernel<<<egrid, THREADS, 0, stream>>>(nodes, eidx, eattr, Wm, agg, E);
  node_kernel<256, 0><<<ngrid, THREADS, 0, stream>>>(nodes, agg, W1, b1, g1, bl1, h, Nn);
  node_kernel<128, 1><<<ngrid, THREADS, 0, stream>>>(h, nullptr, W2, b2, g2, bl2, agg, Nn);
  node_kernel<128, 2><<<ngrid, THREADS, 0, stream>>>(nodes, agg, Wn, nullptr, gf, blf, out, Nn);
}